// Round 8
// baseline (242.897 us; speedup 1.0000x reference)
//
#include <hip/hip_runtime.h>

#define F_IN 128
#define F_OUT 64
#define ROWS_PER_BLOCK 64

#define NPB 128          // nodes per bucket
#define NPB_SHIFT 7
#define BCAP 800         // max buckets (nb = 782)
#define ECAP 2560        // edges staged per LDS chunk in baccum
#define TILE 8192        // edges per block in bscatter multisplit
#define BSTH 1024        // bscatter threads
#define HBLK 256         // gemm blocks that moonlight as histogram blocks

// ---------------------------------------------------------------------------
// Kernel 1 (fused): support = x @ weight  +  edge-bucket histogram + scan.
// gemm is VALU/LDS-bound with idle VMEM; blocks < hblk also histogram a slice
// of edge_dst (dst>>7) into LDS and flush once per bin. The LAST hist block
// (device-scope done counter) scans the 782 bins inline -> offsets/cursors.
// bscatter runs in a later dispatch, so scan completion is stream-ordered.
// ---------------------------------------------------------------------------
__global__ __launch_bounds__(256) void gemm_kernel(const float* __restrict__ x,
                                                   const float* __restrict__ w,
                                                   float* __restrict__ support,
                                                   int n_nodes,
                                                   const int* __restrict__ edge_dst,
                                                   int n_edges,
                                                   int* __restrict__ g_hist,
                                                   int* __restrict__ offsets,
                                                   int* __restrict__ cursors,
                                                   int* __restrict__ done,
                                                   int nb, int hblk) {
    __shared__ float w_lds[F_IN * F_OUT];                 // 32 KB
    __shared__ float x_lds[ROWS_PER_BLOCK][F_IN + 1];     // ~33 KB
    __shared__ int h[BCAP];                               // 3.2 KB
    __shared__ int sscan[256];                            // 1 KB
    __shared__ int is_last;

    const int tid = threadIdx.x;

    // ---- histogram LDS init (ordering covered by the staging barrier) ----
    for (int i = tid; i < BCAP; i += 256) h[i] = 0;
    if (tid == 0) is_last = 0;

    // ---- gemm phase ----
    {
        const float4* w4 = (const float4*)w;
        float4* wl4 = (float4*)w_lds;
        #pragma unroll
        for (int i = tid; i < (F_IN * F_OUT) / 4; i += 256) wl4[i] = w4[i];
    }

    const int row0 = blockIdx.x * ROWS_PER_BLOCK;

    #pragma unroll
    for (int i = tid; i < ROWS_PER_BLOCK * (F_IN / 4); i += 256) {
        const int r   = i >> 5;
        const int k4  = i & 31;
        const int row = row0 + r;
        float4 v = make_float4(0.f, 0.f, 0.f, 0.f);
        if (row < n_nodes) v = ((const float4*)(x + (size_t)row * F_IN))[k4];
        x_lds[r][k4 * 4 + 0] = v.x;
        x_lds[r][k4 * 4 + 1] = v.y;
        x_lds[r][k4 * 4 + 2] = v.z;
        x_lds[r][k4 * 4 + 3] = v.w;
    }
    __syncthreads();

    const int tf = tid & 15;
    const int tr = tid >> 4;

    float acc[4][4] = {};
    #pragma unroll 4
    for (int k = 0; k < F_IN; ++k) {
        const float4 wv = *(const float4*)&w_lds[k * F_OUT + 4 * tf];
        const float x0 = x_lds[4 * tr + 0][k];
        const float x1 = x_lds[4 * tr + 1][k];
        const float x2 = x_lds[4 * tr + 2][k];
        const float x3 = x_lds[4 * tr + 3][k];
        acc[0][0] += x0 * wv.x; acc[0][1] += x0 * wv.y; acc[0][2] += x0 * wv.z; acc[0][3] += x0 * wv.w;
        acc[1][0] += x1 * wv.x; acc[1][1] += x1 * wv.y; acc[1][2] += x1 * wv.z; acc[1][3] += x1 * wv.w;
        acc[2][0] += x2 * wv.x; acc[2][1] += x2 * wv.y; acc[2][2] += x2 * wv.z; acc[2][3] += x2 * wv.w;
        acc[3][0] += x3 * wv.x; acc[3][1] += x3 * wv.y; acc[3][2] += x3 * wv.z; acc[3][3] += x3 * wv.w;
    }

    #pragma unroll
    for (int i = 0; i < 4; ++i) {
        const int row = row0 + 4 * tr + i;
        if (row < n_nodes) {
            float4 v = make_float4(acc[i][0], acc[i][1], acc[i][2], acc[i][3]);
            *(float4*)&support[(size_t)row * F_OUT + 4 * tf] = v;
        }
    }

    // ---- histogram phase (blocks < hblk only) ----
    if (blockIdx.x < hblk) {
        const int n4 = n_edges >> 2;
        const int4* d4 = (const int4*)edge_dst;
        const int stride = hblk * 256;
        for (int t = blockIdx.x * 256 + tid; t < n4; t += stride) {
            const int4 d = d4[t];
            atomicAdd(&h[d.x >> NPB_SHIFT], 1);
            atomicAdd(&h[d.y >> NPB_SHIFT], 1);
            atomicAdd(&h[d.z >> NPB_SHIFT], 1);
            atomicAdd(&h[d.w >> NPB_SHIFT], 1);
        }
        if (blockIdx.x == 0) {   // tail edges (<=3)
            for (int e = (n4 << 2) + tid; e < n_edges; e += 256)
                atomicAdd(&h[edge_dst[e] >> NPB_SHIFT], 1);
        }
        __syncthreads();
        for (int i = tid; i < nb; i += 256)
            if (h[i]) atomicAdd(&g_hist[i], h[i]);

        // ---- last-block inline scan ----
        __threadfence();                     // drain this thread's atomics
        __syncthreads();
        if (tid == 0) is_last = (atomicAdd(done, 1) == hblk - 1) ? 1 : 0;
        __syncthreads();
        if (is_last) {
            const int base = tid * 4;        // coherent reads via atomic RMW
            const int v0 = (base + 0 < nb) ? atomicAdd(&g_hist[base + 0], 0) : 0;
            const int v1 = (base + 1 < nb) ? atomicAdd(&g_hist[base + 1], 0) : 0;
            const int v2 = (base + 2 < nb) ? atomicAdd(&g_hist[base + 2], 0) : 0;
            const int v3 = (base + 3 < nb) ? atomicAdd(&g_hist[base + 3], 0) : 0;
            const int s1 = v0, s2 = s1 + v1, s3 = s2 + v2, s4 = s3 + v3;
            int t = s4;
            sscan[tid] = t;
            __syncthreads();
            #pragma unroll
            for (int off = 1; off < 256; off <<= 1) {
                const int xv = (tid >= off) ? sscan[tid - off] : 0;
                __syncthreads();
                t += xv;
                sscan[tid] = t;
                __syncthreads();
            }
            const int excl = t - s4;
            const int e0 = excl, e1 = excl + s1, e2 = excl + s2, e3 = excl + s3;
            if (base + 0 < nb) { offsets[base + 0] = e0; cursors[base + 0] = e0; }
            if (base + 1 < nb) { offsets[base + 1] = e1; cursors[base + 1] = e1; }
            if (base + 2 < nb) { offsets[base + 2] = e2; cursors[base + 2] = e2; }
            if (base + 3 < nb) { offsets[base + 3] = e3; cursors[base + 3] = e3; }
            if (tid == 255) offsets[nb] = t;   // grand total = n_edges
        }
    }
}

// ---------------------------------------------------------------------------
// Kernel 2: block-level multisplit (unchanged from round 7).
// sorted[pos].x = src | (dstLocal << 20); sorted[pos].y = val bits.
// ---------------------------------------------------------------------------
__global__ __launch_bounds__(BSTH) void bscatter_kernel(const float* __restrict__ edge_val,
                                                        const int* __restrict__ edge_src,
                                                        const int* __restrict__ edge_dst,
                                                        int* __restrict__ cursors,
                                                        int2* __restrict__ sorted,
                                                        int n_edges, int nb) {
    __shared__ int2 ebuf[TILE];                  // 64 KB
    __shared__ unsigned short bkt[TILE];         // 16 KB
    __shared__ unsigned short order[TILE];       // 16 KB
    __shared__ int h[BCAP];                      // 3.2 KB
    __shared__ int sbuf[BSTH];                   // 4 KB
    __shared__ int lcur[BCAP];
    __shared__ int delta[BCAP];

    const int tid = threadIdx.x;
    const int te  = blockIdx.x * TILE;
    const int cnt = min(TILE, n_edges - te);

    for (int i = tid; i < BCAP; i += BSTH) h[i] = 0;
    __syncthreads();

    const int cnt4 = cnt >> 2;
    const int4*   s4 = (const int4*)(edge_src + te);
    const int4*   d4 = (const int4*)(edge_dst + te);
    const float4* v4 = (const float4*)(edge_val + te);
    for (int t = tid; t < cnt4; t += BSTH) {
        const int4   s = s4[t];
        const int4   d = d4[t];
        const float4 v = v4[t];
        const int i = t << 2;
        int b;
        b = d.x >> NPB_SHIFT; bkt[i + 0] = (unsigned short)b; atomicAdd(&h[b], 1);
        ebuf[i + 0] = make_int2(s.x | ((d.x & (NPB - 1)) << 20), __float_as_int(v.x));
        b = d.y >> NPB_SHIFT; bkt[i + 1] = (unsigned short)b; atomicAdd(&h[b], 1);
        ebuf[i + 1] = make_int2(s.y | ((d.y & (NPB - 1)) << 20), __float_as_int(v.y));
        b = d.z >> NPB_SHIFT; bkt[i + 2] = (unsigned short)b; atomicAdd(&h[b], 1);
        ebuf[i + 2] = make_int2(s.z | ((d.z & (NPB - 1)) << 20), __float_as_int(v.z));
        b = d.w >> NPB_SHIFT; bkt[i + 3] = (unsigned short)b; atomicAdd(&h[b], 1);
        ebuf[i + 3] = make_int2(s.w | ((d.w & (NPB - 1)) << 20), __float_as_int(v.w));
    }
    for (int e = (cnt4 << 2) + tid; e < cnt; e += BSTH) {   // tail (<=3)
        const int dd = edge_dst[te + e];
        const int b = dd >> NPB_SHIFT;
        bkt[e] = (unsigned short)b;
        atomicAdd(&h[b], 1);
        ebuf[e] = make_int2(edge_src[te + e] | ((dd & (NPB - 1)) << 20),
                            __float_as_int(edge_val[te + e]));
    }
    __syncthreads();

    sbuf[tid] = (tid < nb) ? h[tid] : 0;
    __syncthreads();
    #pragma unroll
    for (int off = 1; off < BSTH; off <<= 1) {
        const int v = (tid >= off) ? sbuf[tid - off] : 0;
        __syncthreads();
        sbuf[tid] += v;
        __syncthreads();
    }

    if (tid < nb) {
        const int loff = sbuf[tid] - h[tid];
        lcur[tid] = loff;
        if (h[tid] > 0) delta[tid] = atomicAdd(&cursors[tid], h[tid]) - loff;
    }
    __syncthreads();

    for (int i = tid; i < cnt; i += BSTH) {
        const int r = atomicAdd(&lcur[bkt[i]], 1);
        order[r] = (unsigned short)i;
    }
    __syncthreads();

    for (int k = tid; k < cnt; k += BSTH) {
        const int i = order[k];
        sorted[delta[bkt[i]] + k] = ebuf[i];
    }
}

// ---------------------------------------------------------------------------
// Kernel 3 (v3): per-bucket accumulate.
//   Pass 1: hist of dstLocal (coalesced global read of segment).
//   Pass 2: permute records DIRECTLY into LDS ebuf2 (segment re-read = L2 hit)
//           -> hot loop has no order[] indirection.
//   Gather: group of 16 lanes owns nodes g+32j; per edge ONE broadcast
//   ds_read_b64 + 8-wide independent float4 gather batch; register acc;
//   ReLU fused; contiguous 256 B stores.
// ---------------------------------------------------------------------------
__global__ __launch_bounds__(512) void baccum_kernel(const float* __restrict__ support,
                                                     const int2* __restrict__ sorted,
                                                     const int* __restrict__ offsets,
                                                     float* __restrict__ out,
                                                     int n_nodes) {
    __shared__ int2 ebuf2[ECAP];                   // 20 KB, permuted by dstLocal
    __shared__ int hist[NPB];
    __shared__ int scanbuf[NPB];
    __shared__ int node_off[NPB + 1];
    __shared__ int cursor[NPB];

    const int tid = threadIdx.x;
    const int bucket = blockIdx.x;
    const int beg = offsets[bucket];
    const int end = offsets[bucket + 1];

    const int g  = tid >> 4;        // group 0..31
    const int f4 = tid & 15;        // float4 feature index 0..15
    const float4* sup4 = (const float4*)support;

    float4 acc[4];
    #pragma unroll
    for (int j = 0; j < 4; ++j) acc[j] = make_float4(0.f, 0.f, 0.f, 0.f);

    for (int cb = beg; cb < end; cb += ECAP) {
        const int cnt = min(ECAP, end - cb);

        __syncthreads();                        // prev gather done
        if (tid < NPB) hist[tid] = 0;
        __syncthreads();

        // Pass 1: histogram (coalesced segment read).
        for (int i = tid; i < cnt; i += 512)
            atomicAdd(&hist[((unsigned)sorted[cb + i].x) >> 20], 1);
        __syncthreads();

        // Inclusive scan of 128 bins.
        if (tid < NPB) scanbuf[tid] = hist[tid];
        __syncthreads();
        #pragma unroll
        for (int off = 1; off < NPB; off <<= 1) {
            int v = 0;
            if (tid < NPB && tid >= off) v = scanbuf[tid - off];
            __syncthreads();
            if (tid < NPB) scanbuf[tid] += v;
            __syncthreads();
        }
        if (tid < NPB) {
            node_off[tid + 1] = scanbuf[tid];
            cursor[tid] = scanbuf[tid] - hist[tid];   // exclusive start
            if (tid == 0) node_off[0] = 0;
        }
        __syncthreads();

        // Pass 2: permute directly into LDS (segment re-read hits L2).
        for (int i = tid; i < cnt; i += 512) {
            const int2 ev = sorted[cb + i];
            const int r = atomicAdd(&cursor[((unsigned)ev.x) >> 20], 1);
            ebuf2[r] = ev;
        }
        __syncthreads();

        // Register gather, 8-wide independent batches.
        #pragma unroll
        for (int j = 0; j < 4; ++j) {
            const int nl = g + 32 * j;
            int k = node_off[nl];
            const int ke = node_off[nl + 1];
            float4 a = acc[j];
            while (k + 8 <= ke) {
                int2 e[8];
                float4 s[8];
                #pragma unroll
                for (int u = 0; u < 8; ++u) e[u] = ebuf2[k + u];       // broadcast
                #pragma unroll
                for (int u = 0; u < 8; ++u)
                    s[u] = sup4[(size_t)(e[u].x & 0xFFFFF) * 16 + f4]; // independent
                #pragma unroll
                for (int u = 0; u < 8; ++u) {
                    const float v = __int_as_float(e[u].y);
                    a.x += v * s[u].x; a.y += v * s[u].y;
                    a.z += v * s[u].z; a.w += v * s[u].w;
                }
                k += 8;
            }
            for (; k < ke; ++k) {
                const int2 e0 = ebuf2[k];
                const float4 s0 = sup4[(size_t)(e0.x & 0xFFFFF) * 16 + f4];
                const float v0 = __int_as_float(e0.y);
                a.x += v0 * s0.x; a.y += v0 * s0.y; a.z += v0 * s0.z; a.w += v0 * s0.w;
            }
            acc[j] = a;
        }
    }

    // Writeout (empty buckets write zeros; ReLU(0)=0 matches segment_sum).
    const int base = bucket << NPB_SHIFT;
    #pragma unroll
    for (int j = 0; j < 4; ++j) {
        const int node = base + g + 32 * j;
        if (node < n_nodes) {
            float4 v = acc[j];
            v.x = fmaxf(v.x, 0.f); v.y = fmaxf(v.y, 0.f);
            v.z = fmaxf(v.z, 0.f); v.w = fmaxf(v.w, 0.f);
            ((float4*)out)[(size_t)node * 16 + f4] = v;
        }
    }
}

// ---------------------------------------------------------------------------
// Fallback (ws too small / shapes out of packing range): round-1 atomic path.
// ---------------------------------------------------------------------------
__global__ __launch_bounds__(256) void scatter_kernel(const float* __restrict__ support,
                                                      const float* __restrict__ edge_val,
                                                      const int* __restrict__ edge_src,
                                                      const int* __restrict__ edge_dst,
                                                      float* __restrict__ out,
                                                      int n_edges) {
    const long gid = (long)blockIdx.x * blockDim.x + threadIdx.x;
    const int e = (int)(gid >> 4);
    if (e >= n_edges) return;
    const int fo = (int)(gid & 15) * 4;
    const int src   = edge_src[e];
    const int dst   = edge_dst[e];
    const float val = edge_val[e];
    const float4 s = *(const float4*)&support[(size_t)src * F_OUT + fo];
    float* o = &out[(size_t)dst * F_OUT + fo];
    atomicAdd(o + 0, val * s.x);
    atomicAdd(o + 1, val * s.y);
    atomicAdd(o + 2, val * s.z);
    atomicAdd(o + 3, val * s.w);
}

__global__ __launch_bounds__(256) void relu_kernel(float* __restrict__ out, int n4) {
    const int i = blockIdx.x * blockDim.x + threadIdx.x;
    if (i < n4) {
        float4 v = ((float4*)out)[i];
        v.x = fmaxf(v.x, 0.f); v.y = fmaxf(v.y, 0.f);
        v.z = fmaxf(v.z, 0.f); v.w = fmaxf(v.w, 0.f);
        ((float4*)out)[i] = v;
    }
}

extern "C" void kernel_launch(void* const* d_in, const int* in_sizes, int n_in,
                              void* d_out, int out_size, void* d_ws, size_t ws_size,
                              hipStream_t stream) {
    const float* x        = (const float*)d_in[0];
    const float* w        = (const float*)d_in[1];
    const float* edge_val = (const float*)d_in[2];
    const int*   edge_src = (const int*)d_in[3];
    const int*   edge_dst = (const int*)d_in[4];
    float* out = (float*)d_out;

    const int n_nodes = in_sizes[0] / F_IN;   // 100000
    const int n_edges = in_sizes[2];          // 1600000
    const int nb = (n_nodes + NPB - 1) >> NPB_SHIFT;   // 782 buckets

    char* p = (char*)d_ws;
    float* support = (float*)p;  p += (size_t)n_nodes * F_OUT * sizeof(float);
    int2*  sorted  = (int2*)p;   p += (size_t)n_edges * sizeof(int2);
    int*   offsets = (int*)p;    p += (size_t)(nb + 1) * sizeof(int);
    int*   cursors = (int*)p;    p += (size_t)nb * sizeof(int);
    int*   g_hist  = (int*)p;    p += (size_t)nb * sizeof(int);
    int*   done    = (int*)p;    p += sizeof(int);
    const size_t ws_needed = (size_t)(p - (char*)d_ws);

    const int gemm_blocks = (n_nodes + ROWS_PER_BLOCK - 1) / ROWS_PER_BLOCK;  // 1563
    const bool ok = (ws_size >= ws_needed) && (nb <= BCAP) && (n_nodes < (1 << 20))
                    && (gemm_blocks >= HBLK);

    if (ok) {
        // zero g_hist + done in one memset (contiguous in ws layout)
        hipMemsetAsync(g_hist, 0, (size_t)(nb + 1) * sizeof(int), stream);
        gemm_kernel<<<gemm_blocks, 256, 0, stream>>>(x, w, support, n_nodes,
                                                     edge_dst, n_edges, g_hist,
                                                     offsets, cursors, done,
                                                     nb, HBLK);
        const int sblocks = (n_edges + TILE - 1) / TILE;   // 196
        bscatter_kernel<<<sblocks, BSTH, 0, stream>>>(edge_val, edge_src, edge_dst,
                                                      cursors, sorted, n_edges, nb);
        baccum_kernel<<<nb, 512, 0, stream>>>(support, sorted, offsets, out, n_nodes);
    } else {
        gemm_kernel<<<gemm_blocks, 256, 0, stream>>>(x, w, support, n_nodes,
                                                     edge_dst, n_edges, nullptr,
                                                     nullptr, nullptr, nullptr,
                                                     nb, 0);
        hipMemsetAsync(d_out, 0, (size_t)out_size * sizeof(float), stream);
        const long st = (long)n_edges * 16;
        scatter_kernel<<<(int)((st + 255) / 256), 256, 0, stream>>>(
            support, edge_val, edge_src, edge_dst, out, n_edges);
        const int n4o = out_size / 4;
        relu_kernel<<<(n4o + 255) / 256, 256, 0, stream>>>(out, n4o);
    }
}

// Round 9
// 201.848 us; speedup vs baseline: 1.2034x; 1.2034x over previous
//
#include <hip/hip_runtime.h>

#define F_IN 128
#define F_OUT 64
#define ROWS_PER_BLOCK 64
#define XSTRIDE 33       // float4 per x_lds row (132 floats, 16B aligned, padded)

#define NPB 128          // nodes per bucket
#define NPB_SHIFT 7
#define BCAP 800         // max buckets (nb = 782)
#define ECAP 2560        // edges staged per LDS chunk in baccum
#define TILE 8192        // edges per tile in bscatter multisplit
#define BSTH 1024        // bscatter threads
#define TMAX 256         // max tiles (T = ceil(E/TILE) = 196)

// ---------------------------------------------------------------------------
// Kernel 1 (v2): support = x @ weight.  512 threads, 64-row tile.
// LDS 65.8 KB -> 2 blocks/CU = 16 waves/CU (4/SIMD), vs 8 waves at 256 thr.
// x_lds rows stride 33 float4: staging via ds_write_b128 (was 4-way-conflict
// scalar writes); compute reads are 2-way bank aliased (free, m136).
// ---------------------------------------------------------------------------
__global__ __launch_bounds__(512) void gemm_kernel(const float* __restrict__ x,
                                                   const float* __restrict__ w,
                                                   float* __restrict__ support,
                                                   int n_nodes) {
    __shared__ float4 w_lds[F_IN * F_OUT / 4];              // 2048 f4 = 32 KB
    __shared__ float4 x_lds[ROWS_PER_BLOCK * XSTRIDE];      // 33.8 KB

    const int tid = threadIdx.x;

    {   // stage weight: 2048 f4, 4 per thread, coalesced
        const float4* w4 = (const float4*)w;
        #pragma unroll
        for (int i = tid; i < F_IN * F_OUT / 4; i += 512) w_lds[i] = w4[i];
    }

    const int row0 = blockIdx.x * ROWS_PER_BLOCK;
    {   // stage x: 64 rows x 32 f4; b128 LDS writes, coalesced global reads
        const float4* x4 = (const float4*)x;
        #pragma unroll
        for (int i = tid; i < ROWS_PER_BLOCK * (F_IN / 4); i += 512) {
            const int r  = i >> 5;
            const int k4 = i & 31;
            const int row = row0 + r;
            float4 v = make_float4(0.f, 0.f, 0.f, 0.f);
            if (row < n_nodes) v = x4[(size_t)row * (F_IN / 4) + k4];
            x_lds[r * XSTRIDE + k4] = v;
        }
    }
    __syncthreads();

    const int tf = tid & 15;     // feats 4tf..4tf+3
    const int tr = tid >> 4;     // rows tr and tr+32
    const float* xs = (const float*)x_lds;

    float acc[2][4] = {};
    #pragma unroll 4
    for (int k = 0; k < F_IN; ++k) {
        const float4 wv = w_lds[k * 16 + tf];
        const float x0 = xs[tr * (XSTRIDE * 4) + k];
        const float x1 = xs[(tr + 32) * (XSTRIDE * 4) + k];
        acc[0][0] += x0 * wv.x; acc[0][1] += x0 * wv.y; acc[0][2] += x0 * wv.z; acc[0][3] += x0 * wv.w;
        acc[1][0] += x1 * wv.x; acc[1][1] += x1 * wv.y; acc[1][2] += x1 * wv.z; acc[1][3] += x1 * wv.w;
    }

    #pragma unroll
    for (int i = 0; i < 2; ++i) {
        const int row = row0 + tr + 32 * i;
        if (row < n_nodes) {
            float4 v = make_float4(acc[i][0], acc[i][1], acc[i][2], acc[i][3]);
            *(float4*)&support[(size_t)row * F_OUT + 4 * tf] = v;
        }
    }
}

// ---------------------------------------------------------------------------
// Kernel 2 (v4): tile-private multisplit. Each block sorts its TILE of edges
// by bucket IN LDS and writes them back to its OWN region sorted[blk*TILE..]
// (pure streaming store, no cross-block interleave, no global cursors), plus
// the per-(tile,bucket) exclusive offsets toff[blk*(nb+1) + 0..nb].
// sorted rec: x = src | (dstLocal<<20), y = val bits.
// ---------------------------------------------------------------------------
__global__ __launch_bounds__(BSTH) void bscatter_kernel(const float* __restrict__ edge_val,
                                                        const int* __restrict__ edge_src,
                                                        const int* __restrict__ edge_dst,
                                                        int* __restrict__ toff,
                                                        int2* __restrict__ sorted,
                                                        int n_edges, int nb) {
    __shared__ int2 ebuf[TILE];                  // 64 KB
    __shared__ unsigned short bkt[TILE];         // 16 KB
    __shared__ unsigned short order[TILE];       // 16 KB
    __shared__ int h[BCAP];                      // 3.2 KB
    __shared__ int sbuf[BSTH];                   // 4 KB
    __shared__ int lcur[BCAP];                   // 3.2 KB

    const int tid = threadIdx.x;
    const int te  = blockIdx.x * TILE;
    const int cnt = min(TILE, n_edges - te);

    for (int i = tid; i < BCAP; i += BSTH) h[i] = 0;
    __syncthreads();

    const int cnt4 = cnt >> 2;
    const int4*   s4 = (const int4*)(edge_src + te);
    const int4*   d4 = (const int4*)(edge_dst + te);
    const float4* v4 = (const float4*)(edge_val + te);
    for (int t = tid; t < cnt4; t += BSTH) {
        const int4   s = s4[t];
        const int4   d = d4[t];
        const float4 v = v4[t];
        const int i = t << 2;
        int b;
        b = d.x >> NPB_SHIFT; bkt[i + 0] = (unsigned short)b; atomicAdd(&h[b], 1);
        ebuf[i + 0] = make_int2(s.x | ((d.x & (NPB - 1)) << 20), __float_as_int(v.x));
        b = d.y >> NPB_SHIFT; bkt[i + 1] = (unsigned short)b; atomicAdd(&h[b], 1);
        ebuf[i + 1] = make_int2(s.y | ((d.y & (NPB - 1)) << 20), __float_as_int(v.y));
        b = d.z >> NPB_SHIFT; bkt[i + 2] = (unsigned short)b; atomicAdd(&h[b], 1);
        ebuf[i + 2] = make_int2(s.z | ((d.z & (NPB - 1)) << 20), __float_as_int(v.z));
        b = d.w >> NPB_SHIFT; bkt[i + 3] = (unsigned short)b; atomicAdd(&h[b], 1);
        ebuf[i + 3] = make_int2(s.w | ((d.w & (NPB - 1)) << 20), __float_as_int(v.w));
    }
    for (int e = (cnt4 << 2) + tid; e < cnt; e += BSTH) {   // tail (<=3)
        const int dd = edge_dst[te + e];
        const int b = dd >> NPB_SHIFT;
        bkt[e] = (unsigned short)b;
        atomicAdd(&h[b], 1);
        ebuf[e] = make_int2(edge_src[te + e] | ((dd & (NPB - 1)) << 20),
                            __float_as_int(edge_val[te + e]));
    }
    __syncthreads();

    // Inclusive scan of bucket counts (1024-wide Hillis-Steele).
    sbuf[tid] = (tid < nb) ? h[tid] : 0;
    __syncthreads();
    #pragma unroll
    for (int off = 1; off < BSTH; off <<= 1) {
        const int v = (tid >= off) ? sbuf[tid - off] : 0;
        __syncthreads();
        sbuf[tid] += v;
        __syncthreads();
    }

    // Exclusive starts -> lcur + toff table.
    int* trow = toff + (size_t)blockIdx.x * (nb + 1);
    if (tid < nb) {
        const int start = sbuf[tid] - h[tid];
        lcur[tid] = start;
        trow[tid] = start;
    }
    if (tid == 0) trow[nb] = cnt;
    __syncthreads();

    // Rank, then write back to the private region (streaming, coalesced).
    for (int i = tid; i < cnt; i += BSTH) {
        const int r = atomicAdd(&lcur[bkt[i]], 1);
        order[r] = (unsigned short)i;
    }
    __syncthreads();
    for (int k = tid; k < cnt; k += BSTH)
        sorted[(size_t)te + k] = ebuf[order[k]];
}

// ---------------------------------------------------------------------------
// Kernel 3 (v4): per-bucket accumulate from tile-major sorted.
//   - Load per-tile (start,count) for this bucket; scan counts in LDS.
//   - Stage chunk: binary-search tile (8 LDS steps), one global read pass.
//   - LDS counting-sort into ebuf2 by dstLocal; 8-wide register gather;
//     fused ReLU; contiguous 256 B stores.
// ---------------------------------------------------------------------------
__global__ __launch_bounds__(512) void baccum_kernel(const float* __restrict__ support,
                                                     const int2* __restrict__ sorted,
                                                     const int* __restrict__ toff,
                                                     float* __restrict__ out,
                                                     int n_nodes, int T, int nb) {
    __shared__ int2 ebuf[ECAP];                    // 20 KB
    __shared__ int2 ebuf2[ECAP];                   // 20 KB
    __shared__ int tcnt[TMAX];                     // 1 KB (inclusive scan)
    __shared__ int tstart[TMAX];                   // exclusive starts
    __shared__ int toffb[TMAX];                    // per-tile local start
    __shared__ int hist[NPB];
    __shared__ int scanbuf[NPB];
    __shared__ int node_off[NPB + 1];
    __shared__ int cursor[NPB];

    const int tid = threadIdx.x;
    const int b = blockIdx.x;

    // Per-tile counts for this bucket + inclusive scan over TMAX slots.
    int mycnt = 0;
    if (tid < TMAX) {
        if (tid < T) {
            const int s = toff[(size_t)tid * (nb + 1) + b];
            const int e = toff[(size_t)tid * (nb + 1) + b + 1];
            toffb[tid] = s;
            mycnt = e - s;
        }
        tcnt[tid] = mycnt;
    }
    __syncthreads();
    #pragma unroll
    for (int off = 1; off < TMAX; off <<= 1) {
        int v = 0;
        if (tid < TMAX && tid >= off) v = tcnt[tid - off];
        __syncthreads();
        if (tid < TMAX) tcnt[tid] += v;
        __syncthreads();
    }
    if (tid < TMAX) tstart[tid] = tcnt[tid] - mycnt;
    __syncthreads();
    const int total = tcnt[TMAX - 1];

    const int g16 = tid >> 4;       // group 0..31
    const int f4  = tid & 15;       // float4 feature index
    const float4* sup4 = (const float4*)support;

    float4 acc[4];
    #pragma unroll
    for (int j = 0; j < 4; ++j) acc[j] = make_float4(0.f, 0.f, 0.f, 0.f);

    for (int cb = 0; cb < total; cb += ECAP) {
        const int cnt = min(ECAP, total - cb);

        __syncthreads();
        if (tid < NPB) hist[tid] = 0;
        __syncthreads();

        // Stage + histogram (single global pass; tile via binary search).
        for (int i = tid; i < cnt; i += 512) {
            const int g = cb + i;
            int lo = 0, hi = T - 1;
            while (lo < hi) {                     // max t with tstart[t] <= g
                const int mid = (lo + hi + 1) >> 1;
                if (tstart[mid] <= g) lo = mid; else hi = mid - 1;
            }
            const int2 ev = sorted[(size_t)lo * TILE + toffb[lo] + (g - tstart[lo])];
            ebuf[i] = ev;
            atomicAdd(&hist[((unsigned)ev.x) >> 20], 1);
        }
        __syncthreads();

        // Inclusive scan of 128 node bins.
        if (tid < NPB) scanbuf[tid] = hist[tid];
        __syncthreads();
        #pragma unroll
        for (int off = 1; off < NPB; off <<= 1) {
            int v = 0;
            if (tid < NPB && tid >= off) v = scanbuf[tid - off];
            __syncthreads();
            if (tid < NPB) scanbuf[tid] += v;
            __syncthreads();
        }
        if (tid < NPB) {
            node_off[tid + 1] = scanbuf[tid];
            cursor[tid] = scanbuf[tid] - hist[tid];
            if (tid == 0) node_off[0] = 0;
        }
        __syncthreads();

        // Permute into dstLocal-grouped ebuf2 (LDS only).
        for (int i = tid; i < cnt; i += 512) {
            const int2 ev = ebuf[i];
            const int r = atomicAdd(&cursor[((unsigned)ev.x) >> 20], 1);
            ebuf2[r] = ev;
        }
        __syncthreads();

        // Register gather, 8-wide independent batches.
        #pragma unroll
        for (int j = 0; j < 4; ++j) {
            const int nl = g16 + 32 * j;
            int k = node_off[nl];
            const int ke = node_off[nl + 1];
            float4 a = acc[j];
            while (k + 8 <= ke) {
                int2 e[8];
                float4 s[8];
                #pragma unroll
                for (int u = 0; u < 8; ++u) e[u] = ebuf2[k + u];        // broadcast
                #pragma unroll
                for (int u = 0; u < 8; ++u)
                    s[u] = sup4[(size_t)(e[u].x & 0xFFFFF) * 16 + f4];  // independent
                #pragma unroll
                for (int u = 0; u < 8; ++u) {
                    const float v = __int_as_float(e[u].y);
                    a.x += v * s[u].x; a.y += v * s[u].y;
                    a.z += v * s[u].z; a.w += v * s[u].w;
                }
                k += 8;
            }
            for (; k < ke; ++k) {
                const int2 e0 = ebuf2[k];
                const float4 s0 = sup4[(size_t)(e0.x & 0xFFFFF) * 16 + f4];
                const float v0 = __int_as_float(e0.y);
                a.x += v0 * s0.x; a.y += v0 * s0.y; a.z += v0 * s0.z; a.w += v0 * s0.w;
            }
            acc[j] = a;
        }
    }

    // Writeout (empty buckets write zeros; ReLU(0)=0 matches segment_sum).
    const int base = b << NPB_SHIFT;
    #pragma unroll
    for (int j = 0; j < 4; ++j) {
        const int node = base + g16 + 32 * j;
        if (node < n_nodes) {
            float4 v = acc[j];
            v.x = fmaxf(v.x, 0.f); v.y = fmaxf(v.y, 0.f);
            v.z = fmaxf(v.z, 0.f); v.w = fmaxf(v.w, 0.f);
            ((float4*)out)[(size_t)node * 16 + f4] = v;
        }
    }
}

// ---------------------------------------------------------------------------
// Fallback (ws too small / shapes out of range): round-1 atomic path.
// ---------------------------------------------------------------------------
__global__ __launch_bounds__(256) void scatter_kernel(const float* __restrict__ support,
                                                      const float* __restrict__ edge_val,
                                                      const int* __restrict__ edge_src,
                                                      const int* __restrict__ edge_dst,
                                                      float* __restrict__ out,
                                                      int n_edges) {
    const long gid = (long)blockIdx.x * blockDim.x + threadIdx.x;
    const int e = (int)(gid >> 4);
    if (e >= n_edges) return;
    const int fo = (int)(gid & 15) * 4;
    const int src   = edge_src[e];
    const int dst   = edge_dst[e];
    const float val = edge_val[e];
    const float4 s = *(const float4*)&support[(size_t)src * F_OUT + fo];
    float* o = &out[(size_t)dst * F_OUT + fo];
    atomicAdd(o + 0, val * s.x);
    atomicAdd(o + 1, val * s.y);
    atomicAdd(o + 2, val * s.z);
    atomicAdd(o + 3, val * s.w);
}

__global__ __launch_bounds__(256) void relu_kernel(float* __restrict__ out, int n4) {
    const int i = blockIdx.x * blockDim.x + threadIdx.x;
    if (i < n4) {
        float4 v = ((float4*)out)[i];
        v.x = fmaxf(v.x, 0.f); v.y = fmaxf(v.y, 0.f);
        v.z = fmaxf(v.z, 0.f); v.w = fmaxf(v.w, 0.f);
        ((float4*)out)[i] = v;
    }
}

extern "C" void kernel_launch(void* const* d_in, const int* in_sizes, int n_in,
                              void* d_out, int out_size, void* d_ws, size_t ws_size,
                              hipStream_t stream) {
    const float* x        = (const float*)d_in[0];
    const float* w        = (const float*)d_in[1];
    const float* edge_val = (const float*)d_in[2];
    const int*   edge_src = (const int*)d_in[3];
    const int*   edge_dst = (const int*)d_in[4];
    float* out = (float*)d_out;

    const int n_nodes = in_sizes[0] / F_IN;   // 100000
    const int n_edges = in_sizes[2];          // 1600000
    const int nb = (n_nodes + NPB - 1) >> NPB_SHIFT;   // 782 buckets
    const int T  = (n_edges + TILE - 1) / TILE;        // 196 tiles

    // Workspace:
    //   support : n_nodes*F_OUT floats       (25.6 MB)
    //   sorted  : T*TILE int2                (12.85 MB, tile-private regions)
    //   toff    : T*(nb+1) ints              (0.61 MB)
    char* p = (char*)d_ws;
    float* support = (float*)p;  p += (size_t)n_nodes * F_OUT * sizeof(float);
    int2*  sorted  = (int2*)p;   p += (size_t)T * TILE * sizeof(int2);
    int*   toff    = (int*)p;    p += (size_t)T * (nb + 1) * sizeof(int);
    const size_t ws_needed = (size_t)(p - (char*)d_ws);

    const int gemm_blocks = (n_nodes + ROWS_PER_BLOCK - 1) / ROWS_PER_BLOCK;  // 1563
    gemm_kernel<<<gemm_blocks, 512, 0, stream>>>(x, w, support, n_nodes);

    const bool ok = (ws_size >= ws_needed) && (nb <= BCAP) && (n_nodes < (1 << 20))
                    && (T <= TMAX);
    if (ok) {
        bscatter_kernel<<<T, BSTH, 0, stream>>>(edge_val, edge_src, edge_dst,
                                                toff, sorted, n_edges, nb);
        baccum_kernel<<<nb, 512, 0, stream>>>(support, sorted, toff, out,
                                              n_nodes, T, nb);
    } else {
        hipMemsetAsync(d_out, 0, (size_t)out_size * sizeof(float), stream);
        const long st = (long)n_edges * 16;
        scatter_kernel<<<(int)((st + 255) / 256), 256, 0, stream>>>(
            support, edge_val, edge_src, edge_dst, out, n_edges);
        const int n4o = out_size / 4;
        relu_kernel<<<(n4o + 255) / 256, 256, 0, stream>>>(out, n4o);
    }
}

// Round 10
// 181.553 us; speedup vs baseline: 1.3379x; 1.1118x over previous
//
#include <hip/hip_runtime.h>

#define F_IN 128
#define F_OUT 64
#define ROWS_PER_BLOCK 64
#define XSTRIDE 33       // float4 per x_lds row (132 floats, 16B aligned, padded)

#define NPB 128          // nodes per bucket
#define NPB_SHIFT 7
#define BCAP 800         // max buckets (nb = 782)
#define ECAP 2560        // edges staged per LDS chunk in baccum
#define TILE 8192        // edges per tile in bscatter multisplit
#define BSTH 1024        // bscatter threads
#define TMAX 256         // max tiles (T = ceil(E/TILE) = 196)

// fp32 -> bf16 with round-to-nearest-even (bit trick; NaN irrelevant here).
__device__ inline unsigned short f2bf(float f) {
    const unsigned u = __float_as_uint(f);
    return (unsigned short)((u + 0x7FFFu + ((u >> 16) & 1u)) >> 16);
}

// ---------------------------------------------------------------------------
// Kernel 1: support(bf16) = x @ weight.  512 threads, 64-row tile.
// bf16 epilogue: halves support write (12.8 MB) AND the gather row to 128 B.
// ---------------------------------------------------------------------------
__global__ __launch_bounds__(512) void gemm_kernel(const float* __restrict__ x,
                                                   const float* __restrict__ w,
                                                   unsigned short* __restrict__ support,
                                                   int n_nodes) {
    __shared__ float4 w_lds[F_IN * F_OUT / 4];              // 32 KB
    __shared__ float4 x_lds[ROWS_PER_BLOCK * XSTRIDE];      // 33.8 KB

    const int tid = threadIdx.x;

    {   // stage weight: 2048 f4, coalesced
        const float4* w4 = (const float4*)w;
        #pragma unroll
        for (int i = tid; i < F_IN * F_OUT / 4; i += 512) w_lds[i] = w4[i];
    }

    const int row0 = blockIdx.x * ROWS_PER_BLOCK;
    {   // stage x: 64 rows x 32 f4; b128 LDS writes, coalesced global reads
        const float4* x4 = (const float4*)x;
        #pragma unroll
        for (int i = tid; i < ROWS_PER_BLOCK * (F_IN / 4); i += 512) {
            const int r  = i >> 5;
            const int k4 = i & 31;
            const int row = row0 + r;
            float4 v = make_float4(0.f, 0.f, 0.f, 0.f);
            if (row < n_nodes) v = x4[(size_t)row * (F_IN / 4) + k4];
            x_lds[r * XSTRIDE + k4] = v;
        }
    }
    __syncthreads();

    const int tf = tid & 15;     // feats 4tf..4tf+3
    const int tr = tid >> 4;     // rows tr and tr+32
    const float* xs = (const float*)x_lds;

    float acc[2][4] = {};
    #pragma unroll 4
    for (int k = 0; k < F_IN; ++k) {
        const float4 wv = w_lds[k * 16 + tf];
        const float x0 = xs[tr * (XSTRIDE * 4) + k];
        const float x1 = xs[(tr + 32) * (XSTRIDE * 4) + k];
        acc[0][0] += x0 * wv.x; acc[0][1] += x0 * wv.y; acc[0][2] += x0 * wv.z; acc[0][3] += x0 * wv.w;
        acc[1][0] += x1 * wv.x; acc[1][1] += x1 * wv.y; acc[1][2] += x1 * wv.z; acc[1][3] += x1 * wv.w;
    }

    #pragma unroll
    for (int i = 0; i < 2; ++i) {
        const int row = row0 + tr + 32 * i;
        if (row < n_nodes) {
            ushort4 o;
            o.x = f2bf(acc[i][0]); o.y = f2bf(acc[i][1]);
            o.z = f2bf(acc[i][2]); o.w = f2bf(acc[i][3]);
            *(ushort4*)&support[(size_t)row * F_OUT + 4 * tf] = o;  // 8B, coalesced
        }
    }
}

// ---------------------------------------------------------------------------
// Kernel 2: tile-private multisplit (round-9 structure; shuffle-based scan
// replaces the 1024-wide Hillis-Steele: 20 barriers -> 2).
// sorted rec: x = src | (dstLocal<<20), y = val bits.
// ---------------------------------------------------------------------------
__global__ __launch_bounds__(BSTH) void bscatter_kernel(const float* __restrict__ edge_val,
                                                        const int* __restrict__ edge_src,
                                                        const int* __restrict__ edge_dst,
                                                        int* __restrict__ toff,
                                                        int2* __restrict__ sorted,
                                                        int n_edges, int nb) {
    __shared__ int2 ebuf[TILE];                  // 64 KB
    __shared__ unsigned short bkt[TILE];         // 16 KB
    __shared__ unsigned short order[TILE];       // 16 KB
    __shared__ int h[BCAP];                      // 3.2 KB
    __shared__ int lcur[BCAP];                   // 3.2 KB
    __shared__ int wsum[16];
    __shared__ int woff_s[16];

    const int tid = threadIdx.x;
    const int te  = blockIdx.x * TILE;
    const int cnt = min(TILE, n_edges - te);

    for (int i = tid; i < BCAP; i += BSTH) h[i] = 0;
    __syncthreads();

    const int cnt4 = cnt >> 2;
    const int4*   s4 = (const int4*)(edge_src + te);
    const int4*   d4 = (const int4*)(edge_dst + te);
    const float4* v4 = (const float4*)(edge_val + te);
    for (int t = tid; t < cnt4; t += BSTH) {
        const int4   s = s4[t];
        const int4   d = d4[t];
        const float4 v = v4[t];
        const int i = t << 2;
        int b;
        b = d.x >> NPB_SHIFT; bkt[i + 0] = (unsigned short)b; atomicAdd(&h[b], 1);
        ebuf[i + 0] = make_int2(s.x | ((d.x & (NPB - 1)) << 20), __float_as_int(v.x));
        b = d.y >> NPB_SHIFT; bkt[i + 1] = (unsigned short)b; atomicAdd(&h[b], 1);
        ebuf[i + 1] = make_int2(s.y | ((d.y & (NPB - 1)) << 20), __float_as_int(v.y));
        b = d.z >> NPB_SHIFT; bkt[i + 2] = (unsigned short)b; atomicAdd(&h[b], 1);
        ebuf[i + 2] = make_int2(s.z | ((d.z & (NPB - 1)) << 20), __float_as_int(v.z));
        b = d.w >> NPB_SHIFT; bkt[i + 3] = (unsigned short)b; atomicAdd(&h[b], 1);
        ebuf[i + 3] = make_int2(s.w | ((d.w & (NPB - 1)) << 20), __float_as_int(v.w));
    }
    for (int e = (cnt4 << 2) + tid; e < cnt; e += BSTH) {   // tail (<=3)
        const int dd = edge_dst[te + e];
        const int b = dd >> NPB_SHIFT;
        bkt[e] = (unsigned short)b;
        atomicAdd(&h[b], 1);
        ebuf[e] = make_int2(edge_src[te + e] | ((dd & (NPB - 1)) << 20),
                            __float_as_int(edge_val[te + e]));
    }
    __syncthreads();

    // Shuffle-based block scan of bucket counts.
    const int v = (tid < nb) ? h[tid] : 0;
    int s = v;
    #pragma unroll
    for (int off = 1; off < 64; off <<= 1) {
        const int t = __shfl_up(s, off, 64);
        if ((tid & 63) >= off) s += t;
    }
    const int wave = tid >> 6;
    if ((tid & 63) == 63) wsum[wave] = s;
    __syncthreads();
    if (tid < 16) {
        const int ws = wsum[tid];
        int sc = ws;
        #pragma unroll
        for (int off = 1; off < 16; off <<= 1) {
            const int t = __shfl_up(sc, off, 64);
            if (tid >= off) sc += t;
        }
        woff_s[tid] = sc - ws;   // exclusive wave offset
    }
    __syncthreads();

    int* trow = toff + (size_t)blockIdx.x * (nb + 1);
    if (tid < nb) {
        const int start = s + woff_s[wave] - v;   // exclusive start
        lcur[tid] = start;
        trow[tid] = start;
    }
    if (tid == 0) trow[nb] = cnt;
    __syncthreads();

    // Rank, then write back to the private region (streaming, coalesced).
    for (int i = tid; i < cnt; i += BSTH) {
        const int r = atomicAdd(&lcur[bkt[i]], 1);
        order[r] = (unsigned short)i;
    }
    __syncthreads();
    for (int k = tid; k < cnt; k += BSTH)
        sorted[(size_t)te + k] = ebuf[order[k]];
}

// ---------------------------------------------------------------------------
// Kernel 3: per-bucket accumulate from tile-major sorted; bf16 support rows
// (uint2 = 4 feats / lane); shuffle scans; 8-wide register gather; fused ReLU.
// ---------------------------------------------------------------------------
__global__ __launch_bounds__(512) void baccum_kernel(const unsigned short* __restrict__ support,
                                                     const int2* __restrict__ sorted,
                                                     const int* __restrict__ toff,
                                                     float* __restrict__ out,
                                                     int n_nodes, int T, int nb) {
    __shared__ int2 ebuf[ECAP];                    // 20 KB
    __shared__ int2 ebuf2[ECAP];                   // 20 KB
    __shared__ int tstart[TMAX];
    __shared__ int toffb[TMAX];
    __shared__ int wsum3[4];
    __shared__ int total_s;
    __shared__ int hist[NPB];
    __shared__ int node_off[NPB + 1];
    __shared__ int cursor[NPB];
    __shared__ int wsum2[2];

    const int tid = threadIdx.x;
    const int b = blockIdx.x;

    // Per-tile counts for this bucket; shuffle scan over 4 waves (T<=256).
    int mycnt = 0, myoff = 0;
    if (tid < TMAX) {
        if (tid < T) {
            const int s0 = toff[(size_t)tid * (nb + 1) + b];
            const int e0 = toff[(size_t)tid * (nb + 1) + b + 1];
            toffb[tid] = s0;
            mycnt = e0 - s0;
        }
        int s = mycnt;
        #pragma unroll
        for (int off = 1; off < 64; off <<= 1) {
            const int t = __shfl_up(s, off, 64);
            if ((tid & 63) >= off) s += t;
        }
        if ((tid & 63) == 63) wsum3[tid >> 6] = s;
        myoff = s - mycnt;   // intra-wave exclusive
    }
    __syncthreads();
    if (tid < TMAX && tid < T) {
        int add = 0;
        const int wv = tid >> 6;
        for (int q = 0; q < wv; ++q) add += wsum3[q];
        tstart[tid] = myoff + add;
    }
    if (tid == 0) total_s = wsum3[0] + wsum3[1] + wsum3[2] + wsum3[3];
    __syncthreads();
    const int total = total_s;

    const int g16 = tid >> 4;       // group 0..31
    const int f4  = tid & 15;       // 4-feat slot
    const uint2* sup = (const uint2*)support;   // row = 16 uint2 = 128 B

    float4 acc[4];
    #pragma unroll
    for (int j = 0; j < 4; ++j) acc[j] = make_float4(0.f, 0.f, 0.f, 0.f);

    for (int cb = 0; cb < total; cb += ECAP) {
        const int cnt = min(ECAP, total - cb);

        __syncthreads();
        if (tid < NPB) hist[tid] = 0;
        __syncthreads();

        // Stage + histogram (tile via binary search over tstart).
        for (int i = tid; i < cnt; i += 512) {
            const int g = cb + i;
            int lo = 0, hi = T - 1;
            while (lo < hi) {
                const int mid = (lo + hi + 1) >> 1;
                if (tstart[mid] <= g) lo = mid; else hi = mid - 1;
            }
            const int2 ev = sorted[(size_t)lo * TILE + toffb[lo] + (g - tstart[lo])];
            ebuf[i] = ev;
            atomicAdd(&hist[((unsigned)ev.x) >> 20], 1);
        }
        __syncthreads();

        // Shuffle scan of 128 node bins (2 waves).
        {
            int v = 0;
            if (tid < NPB) v = hist[tid];
            int s = v;
            if (tid < NPB) {
                #pragma unroll
                for (int off = 1; off < 64; off <<= 1) {
                    const int t = __shfl_up(s, off, 64);
                    if ((tid & 63) >= off) s += t;
                }
                if ((tid & 63) == 63) wsum2[tid >> 6] = s;
            }
            __syncthreads();
            if (tid < NPB) {
                const int incl = s + ((tid >= 64) ? wsum2[0] : 0);
                node_off[tid + 1] = incl;
                cursor[tid] = incl - v;
                if (tid == 0) node_off[0] = 0;
            }
        }
        __syncthreads();

        // Permute into dstLocal-grouped ebuf2 (LDS only).
        for (int i = tid; i < cnt; i += 512) {
            const int2 ev = ebuf[i];
            const int r = atomicAdd(&cursor[((unsigned)ev.x) >> 20], 1);
            ebuf2[r] = ev;
        }
        __syncthreads();

        // Register gather, 8-wide independent bf16-row batches.
        #pragma unroll
        for (int j = 0; j < 4; ++j) {
            const int nl = g16 + 32 * j;
            int k = node_off[nl];
            const int ke = node_off[nl + 1];
            float4 a = acc[j];
            while (k + 8 <= ke) {
                int2 e[8];
                uint2 s[8];
                #pragma unroll
                for (int u = 0; u < 8; ++u) e[u] = ebuf2[k + u];        // broadcast
                #pragma unroll
                for (int u = 0; u < 8; ++u)
                    s[u] = sup[(size_t)(e[u].x & 0xFFFFF) * 16 + f4];   // independent
                #pragma unroll
                for (int u = 0; u < 8; ++u) {
                    const float v = __int_as_float(e[u].y);
                    a.x += v * __uint_as_float(s[u].x << 16);
                    a.y += v * __uint_as_float(s[u].x & 0xFFFF0000u);
                    a.z += v * __uint_as_float(s[u].y << 16);
                    a.w += v * __uint_as_float(s[u].y & 0xFFFF0000u);
                }
                k += 8;
            }
            for (; k < ke; ++k) {
                const int2 e0 = ebuf2[k];
                const uint2 s0 = sup[(size_t)(e0.x & 0xFFFFF) * 16 + f4];
                const float v0 = __int_as_float(e0.y);
                a.x += v0 * __uint_as_float(s0.x << 16);
                a.y += v0 * __uint_as_float(s0.x & 0xFFFF0000u);
                a.z += v0 * __uint_as_float(s0.y << 16);
                a.w += v0 * __uint_as_float(s0.y & 0xFFFF0000u);
            }
            acc[j] = a;
        }
    }

    // Writeout (empty buckets write zeros; ReLU(0)=0 matches segment_sum).
    const int base = b << NPB_SHIFT;
    #pragma unroll
    for (int j = 0; j < 4; ++j) {
        const int node = base + g16 + 32 * j;
        if (node < n_nodes) {
            float4 v = acc[j];
            v.x = fmaxf(v.x, 0.f); v.y = fmaxf(v.y, 0.f);
            v.z = fmaxf(v.z, 0.f); v.w = fmaxf(v.w, 0.f);
            ((float4*)out)[(size_t)node * 16 + f4] = v;
        }
    }
}

// ---------------------------------------------------------------------------
// Fallback (ws too small / shapes out of range): atomic path, bf16 support.
// ---------------------------------------------------------------------------
__global__ __launch_bounds__(256) void scatter_kernel(const unsigned short* __restrict__ support,
                                                      const float* __restrict__ edge_val,
                                                      const int* __restrict__ edge_src,
                                                      const int* __restrict__ edge_dst,
                                                      float* __restrict__ out,
                                                      int n_edges) {
    const long gid = (long)blockIdx.x * blockDim.x + threadIdx.x;
    const int e = (int)(gid >> 4);
    if (e >= n_edges) return;
    const int q = (int)(gid & 15);            // 4-feat slot
    const int src   = edge_src[e];
    const int dst   = edge_dst[e];
    const float val = edge_val[e];
    const uint2 s = ((const uint2*)support)[(size_t)src * 16 + q];
    float* o = &out[(size_t)dst * F_OUT + q * 4];
    atomicAdd(o + 0, val * __uint_as_float(s.x << 16));
    atomicAdd(o + 1, val * __uint_as_float(s.x & 0xFFFF0000u));
    atomicAdd(o + 2, val * __uint_as_float(s.y << 16));
    atomicAdd(o + 3, val * __uint_as_float(s.y & 0xFFFF0000u));
}

__global__ __launch_bounds__(256) void relu_kernel(float* __restrict__ out, int n4) {
    const int i = blockIdx.x * blockDim.x + threadIdx.x;
    if (i < n4) {
        float4 v = ((float4*)out)[i];
        v.x = fmaxf(v.x, 0.f); v.y = fmaxf(v.y, 0.f);
        v.z = fmaxf(v.z, 0.f); v.w = fmaxf(v.w, 0.f);
        ((float4*)out)[i] = v;
    }
}

extern "C" void kernel_launch(void* const* d_in, const int* in_sizes, int n_in,
                              void* d_out, int out_size, void* d_ws, size_t ws_size,
                              hipStream_t stream) {
    const float* x        = (const float*)d_in[0];
    const float* w        = (const float*)d_in[1];
    const float* edge_val = (const float*)d_in[2];
    const int*   edge_src = (const int*)d_in[3];
    const int*   edge_dst = (const int*)d_in[4];
    float* out = (float*)d_out;

    const int n_nodes = in_sizes[0] / F_IN;   // 100000
    const int n_edges = in_sizes[2];          // 1600000
    const int nb = (n_nodes + NPB - 1) >> NPB_SHIFT;   // 782 buckets
    const int T  = (n_edges + TILE - 1) / TILE;        // 196 tiles

    // Workspace:
    //   support : n_nodes*F_OUT bf16         (12.8 MB)
    //   sorted  : T*TILE int2                (12.85 MB, tile-private regions)
    //   toff    : T*(nb+1) ints              (0.61 MB)
    char* p = (char*)d_ws;
    unsigned short* support = (unsigned short*)p;
    p += (size_t)n_nodes * F_OUT * sizeof(unsigned short);
    p = (char*)(((size_t)p + 15) & ~(size_t)15);
    int2* sorted = (int2*)p;  p += (size_t)T * TILE * sizeof(int2);
    int*  toff   = (int*)p;   p += (size_t)T * (nb + 1) * sizeof(int);
    const size_t ws_needed = (size_t)(p - (char*)d_ws);

    const int gemm_blocks = (n_nodes + ROWS_PER_BLOCK - 1) / ROWS_PER_BLOCK;  // 1563
    gemm_kernel<<<gemm_blocks, 512, 0, stream>>>(x, w, support, n_nodes);

    const bool ok = (ws_size >= ws_needed) && (nb <= BCAP) && (n_nodes < (1 << 20))
                    && (T <= TMAX);
    if (ok) {
        bscatter_kernel<<<T, BSTH, 0, stream>>>(edge_val, edge_src, edge_dst,
                                                toff, sorted, n_edges, nb);
        baccum_kernel<<<nb, 512, 0, stream>>>(support, sorted, toff, out,
                                              n_nodes, T, nb);
    } else {
        hipMemsetAsync(d_out, 0, (size_t)out_size * sizeof(float), stream);
        const long st = (long)n_edges * 16;
        scatter_kernel<<<(int)((st + 255) / 256), 256, 0, stream>>>(
            support, edge_val, edge_src, edge_dst, out, n_edges);
        const int n4o = out_size / 4;
        relu_kernel<<<(n4o + 255) / 256, 256, 0, stream>>>(out, n4o);
    }
}

// Round 11
// 179.627 us; speedup vs baseline: 1.3522x; 1.0107x over previous
//
#include <hip/hip_runtime.h>

#define F_IN 128
#define F_OUT 64
#define ROWS_PER_BLOCK 64
#define XSTRIDE 33       // float4 per x_lds row (132 floats, 16B aligned, padded)

#define NPB 128          // nodes per bucket
#define NPB_SHIFT 7
#define BCAP 800         // max buckets (nb = 782)
#define ECAP 2560        // edges staged per LDS chunk in baccum
#define TILE 8192        // edges per tile in multisplit
#define BSTH 1024        // fused-kernel threads
#define TMAX 256         // max tiles (T = ceil(E/TILE) = 196)

// fp32 -> bf16 round-to-nearest-even.
__device__ inline unsigned short f2bf(float f) {
    const unsigned u = __float_as_uint(f);
    return (unsigned short)((u + 0x7FFFu + ((u >> 16) & 1u)) >> 16);
}

// Shared-memory union: gemm role vs multisplit role (whole-block roles).
struct GemmSh {
    float4 w[F_IN * F_OUT / 4];              // 32 KB
    float4 xt[ROWS_PER_BLOCK * XSTRIDE];     // 33.8 KB
};
struct ScatSh {
    int2 ebuf2[TILE];                        // 64 KB (rank-permuted records)
    int  h[BCAP];                            // 3.2 KB
    int  lcur[BCAP];                         // 3.2 KB
    int  wsum[16];
    int  woff[16];
};
union FusedSh { GemmSh g; ScatSh s; };       // ~70.4 KB -> 2 blocks/CU

// ---------------------------------------------------------------------------
// Fused kernel: blocks [0,T) do the tile-private edge multisplit; blocks
// [T, T+G) do support(bf16) = x @ weight. The two jobs are data-independent,
// so one dispatch overlaps the VALU-bound gemm with the LDS/atomic-bound
// multisplit (separate pipes co-schedule, m114).
// ---------------------------------------------------------------------------
__global__ __launch_bounds__(BSTH) void fused_kernel(const float* __restrict__ x,
                                                     const float* __restrict__ w,
                                                     unsigned short* __restrict__ support,
                                                     int n_nodes,
                                                     const float* __restrict__ edge_val,
                                                     const int* __restrict__ edge_src,
                                                     const int* __restrict__ edge_dst,
                                                     int* __restrict__ toff,
                                                     int2* __restrict__ sorted,
                                                     int n_edges, int nb, int T) {
    __shared__ FusedSh u;
    const int tid = threadIdx.x;

    if ((int)blockIdx.x >= T) {
        // ================= gemm role =================
        const int row0 = (blockIdx.x - T) * ROWS_PER_BLOCK;

        {   // stage weight: 2048 f4, 2 per thread
            const float4* w4 = (const float4*)w;
            #pragma unroll
            for (int i = tid; i < F_IN * F_OUT / 4; i += BSTH) u.g.w[i] = w4[i];
        }
        {   // stage x tile: 64 rows x 32 f4
            const float4* x4 = (const float4*)x;
            #pragma unroll
            for (int i = tid; i < ROWS_PER_BLOCK * (F_IN / 4); i += BSTH) {
                const int r  = i >> 5;
                const int k4 = i & 31;
                const int row = row0 + r;
                float4 v = make_float4(0.f, 0.f, 0.f, 0.f);
                if (row < n_nodes) v = x4[(size_t)row * (F_IN / 4) + k4];
                u.g.xt[r * XSTRIDE + k4] = v;
            }
        }
        __syncthreads();

        const int tf = tid & 15;     // feats 4tf..4tf+3
        const int tr = tid >> 4;     // row 0..63
        const float* xs = (const float*)u.g.xt;

        float a0 = 0.f, a1 = 0.f, a2 = 0.f, a3 = 0.f;
        #pragma unroll 4
        for (int k = 0; k < F_IN; ++k) {
            const float4 wv = u.g.w[k * 16 + tf];
            const float xv = xs[tr * (XSTRIDE * 4) + k];   // wave: 4 addrs, broadcast
            a0 += xv * wv.x; a1 += xv * wv.y; a2 += xv * wv.z; a3 += xv * wv.w;
        }
        const int row = row0 + tr;
        if (row < n_nodes) {
            ushort4 o;
            o.x = f2bf(a0); o.y = f2bf(a1); o.z = f2bf(a2); o.w = f2bf(a3);
            *(ushort4*)&support[(size_t)row * F_OUT + 4 * tf] = o;
        }
        return;
    }

    // ================= multisplit role =================
    const int te  = blockIdx.x * TILE;
    const int cnt = min(TILE, n_edges - te);

    for (int i = tid; i < BCAP; i += BSTH) u.s.h[i] = 0;
    __syncthreads();

    // Pass A: load edges into REGISTERS (exactly 2 int4-tiles/thread) + hist.
    const int cnt4 = cnt >> 2;
    const int4*   s4 = (const int4*)(edge_src + te);
    const int4*   d4 = (const int4*)(edge_dst + te);
    const float4* v4 = (const float4*)(edge_val + te);
    int4 rs[2], rd[2]; float4 rv[2];
    #pragma unroll
    for (int it = 0; it < 2; ++it) {
        const int t = tid + it * BSTH;
        if (t < cnt4) {
            rs[it] = s4[t]; rd[it] = d4[t]; rv[it] = v4[t];
            atomicAdd(&u.s.h[rd[it].x >> NPB_SHIFT], 1);
            atomicAdd(&u.s.h[rd[it].y >> NPB_SHIFT], 1);
            atomicAdd(&u.s.h[rd[it].z >> NPB_SHIFT], 1);
            atomicAdd(&u.s.h[rd[it].w >> NPB_SHIFT], 1);
        }
    }
    if (tid == 0) {   // tail (<=3 edges): hist only, ranked in pass B
        for (int e = cnt4 << 2; e < cnt; ++e)
            atomicAdd(&u.s.h[edge_dst[te + e] >> NPB_SHIFT], 1);
    }
    __syncthreads();

    // Shuffle-based block scan of bucket counts (16 waves).
    const int v = (tid < nb) ? u.s.h[tid] : 0;
    int s = v;
    #pragma unroll
    for (int off = 1; off < 64; off <<= 1) {
        const int t = __shfl_up(s, off, 64);
        if ((tid & 63) >= off) s += t;
    }
    const int wave = tid >> 6;
    if ((tid & 63) == 63) u.s.wsum[wave] = s;
    __syncthreads();
    if (tid < 16) {
        const int ws = u.s.wsum[tid];
        int sc = ws;
        #pragma unroll
        for (int off = 1; off < 16; off <<= 1) {
            const int t = __shfl_up(sc, off, 64);
            if (tid >= off) sc += t;
        }
        u.s.woff[tid] = sc - ws;   // exclusive wave offset
    }
    __syncthreads();

    int* trow = toff + (size_t)blockIdx.x * (nb + 1);
    if (tid < nb) {
        const int start = s + u.s.woff[wave] - v;   // exclusive start
        u.s.lcur[tid] = start;
        trow[tid] = start;
    }
    if (tid == 0) trow[nb] = cnt;
    __syncthreads();

    // Pass B: rank (LDS cursor) and write records DIRECTLY permuted into LDS.
    #pragma unroll
    for (int it = 0; it < 2; ++it) {
        const int t = tid + it * BSTH;
        if (t < cnt4) {
            int b, r;
            b = rd[it].x >> NPB_SHIFT; r = atomicAdd(&u.s.lcur[b], 1);
            u.s.ebuf2[r] = make_int2(rs[it].x | ((rd[it].x & (NPB - 1)) << 20), __float_as_int(rv[it].x));
            b = rd[it].y >> NPB_SHIFT; r = atomicAdd(&u.s.lcur[b], 1);
            u.s.ebuf2[r] = make_int2(rs[it].y | ((rd[it].y & (NPB - 1)) << 20), __float_as_int(rv[it].y));
            b = rd[it].z >> NPB_SHIFT; r = atomicAdd(&u.s.lcur[b], 1);
            u.s.ebuf2[r] = make_int2(rs[it].z | ((rd[it].z & (NPB - 1)) << 20), __float_as_int(rv[it].z));
            b = rd[it].w >> NPB_SHIFT; r = atomicAdd(&u.s.lcur[b], 1);
            u.s.ebuf2[r] = make_int2(rs[it].w | ((rd[it].w & (NPB - 1)) << 20), __float_as_int(rv[it].w));
        }
    }
    if (tid == 0) {   // tail
        for (int e = cnt4 << 2; e < cnt; ++e) {
            const int dd = edge_dst[te + e];
            const int b = dd >> NPB_SHIFT;
            const int r = atomicAdd(&u.s.lcur[b], 1);
            u.s.ebuf2[r] = make_int2(edge_src[te + e] | ((dd & (NPB - 1)) << 20),
                                     __float_as_int(edge_val[te + e]));
        }
    }
    __syncthreads();

    // Pass C: stream the sorted tile to its private region (coalesced).
    for (int k = tid; k < cnt; k += BSTH)
        sorted[(size_t)te + k] = u.s.ebuf2[k];
}

// ---------------------------------------------------------------------------
// baccum (unchanged from round 10): per-bucket accumulate, bf16 support rows,
// shuffle scans, LDS counting-sort, 8-wide register gather, fused ReLU.
// ---------------------------------------------------------------------------
__global__ __launch_bounds__(512) void baccum_kernel(const unsigned short* __restrict__ support,
                                                     const int2* __restrict__ sorted,
                                                     const int* __restrict__ toff,
                                                     float* __restrict__ out,
                                                     int n_nodes, int T, int nb) {
    __shared__ int2 ebuf[ECAP];
    __shared__ int2 ebuf2[ECAP];
    __shared__ int tstart[TMAX];
    __shared__ int toffb[TMAX];
    __shared__ int wsum3[4];
    __shared__ int total_s;
    __shared__ int hist[NPB];
    __shared__ int node_off[NPB + 1];
    __shared__ int cursor[NPB];
    __shared__ int wsum2[2];

    const int tid = threadIdx.x;
    const int b = blockIdx.x;

    int mycnt = 0, myoff = 0;
    if (tid < TMAX) {
        if (tid < T) {
            const int s0 = toff[(size_t)tid * (nb + 1) + b];
            const int e0 = toff[(size_t)tid * (nb + 1) + b + 1];
            toffb[tid] = s0;
            mycnt = e0 - s0;
        }
        int s = mycnt;
        #pragma unroll
        for (int off = 1; off < 64; off <<= 1) {
            const int t = __shfl_up(s, off, 64);
            if ((tid & 63) >= off) s += t;
        }
        if ((tid & 63) == 63) wsum3[tid >> 6] = s;
        myoff = s - mycnt;
    }
    __syncthreads();
    if (tid < TMAX && tid < T) {
        int add = 0;
        const int wv = tid >> 6;
        for (int q = 0; q < wv; ++q) add += wsum3[q];
        tstart[tid] = myoff + add;
    }
    if (tid == 0) total_s = wsum3[0] + wsum3[1] + wsum3[2] + wsum3[3];
    __syncthreads();
    const int total = total_s;

    const int g16 = tid >> 4;
    const int f4  = tid & 15;
    const uint2* sup = (const uint2*)support;

    float4 acc[4];
    #pragma unroll
    for (int j = 0; j < 4; ++j) acc[j] = make_float4(0.f, 0.f, 0.f, 0.f);

    for (int cb = 0; cb < total; cb += ECAP) {
        const int cnt = min(ECAP, total - cb);

        __syncthreads();
        if (tid < NPB) hist[tid] = 0;
        __syncthreads();

        for (int i = tid; i < cnt; i += 512) {
            const int g = cb + i;
            int lo = 0, hi = T - 1;
            while (lo < hi) {
                const int mid = (lo + hi + 1) >> 1;
                if (tstart[mid] <= g) lo = mid; else hi = mid - 1;
            }
            const int2 ev = sorted[(size_t)lo * TILE + toffb[lo] + (g - tstart[lo])];
            ebuf[i] = ev;
            atomicAdd(&hist[((unsigned)ev.x) >> 20], 1);
        }
        __syncthreads();

        {
            int v = 0;
            if (tid < NPB) v = hist[tid];
            int s = v;
            if (tid < NPB) {
                #pragma unroll
                for (int off = 1; off < 64; off <<= 1) {
                    const int t = __shfl_up(s, off, 64);
                    if ((tid & 63) >= off) s += t;
                }
                if ((tid & 63) == 63) wsum2[tid >> 6] = s;
            }
            __syncthreads();
            if (tid < NPB) {
                const int incl = s + ((tid >= 64) ? wsum2[0] : 0);
                node_off[tid + 1] = incl;
                cursor[tid] = incl - v;
                if (tid == 0) node_off[0] = 0;
            }
        }
        __syncthreads();

        for (int i = tid; i < cnt; i += 512) {
            const int2 ev = ebuf[i];
            const int r = atomicAdd(&cursor[((unsigned)ev.x) >> 20], 1);
            ebuf2[r] = ev;
        }
        __syncthreads();

        #pragma unroll
        for (int j = 0; j < 4; ++j) {
            const int nl = g16 + 32 * j;
            int k = node_off[nl];
            const int ke = node_off[nl + 1];
            float4 a = acc[j];
            while (k + 8 <= ke) {
                int2 e[8];
                uint2 s[8];
                #pragma unroll
                for (int u2 = 0; u2 < 8; ++u2) e[u2] = ebuf2[k + u2];
                #pragma unroll
                for (int u2 = 0; u2 < 8; ++u2)
                    s[u2] = sup[(size_t)(e[u2].x & 0xFFFFF) * 16 + f4];
                #pragma unroll
                for (int u2 = 0; u2 < 8; ++u2) {
                    const float v = __int_as_float(e[u2].y);
                    a.x += v * __uint_as_float(s[u2].x << 16);
                    a.y += v * __uint_as_float(s[u2].x & 0xFFFF0000u);
                    a.z += v * __uint_as_float(s[u2].y << 16);
                    a.w += v * __uint_as_float(s[u2].y & 0xFFFF0000u);
                }
                k += 8;
            }
            for (; k < ke; ++k) {
                const int2 e0 = ebuf2[k];
                const uint2 s0 = sup[(size_t)(e0.x & 0xFFFFF) * 16 + f4];
                const float v0 = __int_as_float(e0.y);
                a.x += v0 * __uint_as_float(s0.x << 16);
                a.y += v0 * __uint_as_float(s0.x & 0xFFFF0000u);
                a.z += v0 * __uint_as_float(s0.y << 16);
                a.w += v0 * __uint_as_float(s0.y & 0xFFFF0000u);
            }
            acc[j] = a;
        }
    }

    const int base = b << NPB_SHIFT;
    #pragma unroll
    for (int j = 0; j < 4; ++j) {
        const int node = base + g16 + 32 * j;
        if (node < n_nodes) {
            float4 v = acc[j];
            v.x = fmaxf(v.x, 0.f); v.y = fmaxf(v.y, 0.f);
            v.z = fmaxf(v.z, 0.f); v.w = fmaxf(v.w, 0.f);
            ((float4*)out)[(size_t)node * 16 + f4] = v;
        }
    }
}

// ---------------------------------------------------------------------------
// Fallback: atomic path with bf16 support.
// ---------------------------------------------------------------------------
__global__ __launch_bounds__(256) void scatter_kernel(const unsigned short* __restrict__ support,
                                                      const float* __restrict__ edge_val,
                                                      const int* __restrict__ edge_src,
                                                      const int* __restrict__ edge_dst,
                                                      float* __restrict__ out,
                                                      int n_edges) {
    const long gid = (long)blockIdx.x * blockDim.x + threadIdx.x;
    const int e = (int)(gid >> 4);
    if (e >= n_edges) return;
    const int q = (int)(gid & 15);
    const int src   = edge_src[e];
    const int dst   = edge_dst[e];
    const float val = edge_val[e];
    const uint2 s = ((const uint2*)support)[(size_t)src * 16 + q];
    float* o = &out[(size_t)dst * F_OUT + q * 4];
    atomicAdd(o + 0, val * __uint_as_float(s.x << 16));
    atomicAdd(o + 1, val * __uint_as_float(s.x & 0xFFFF0000u));
    atomicAdd(o + 2, val * __uint_as_float(s.y << 16));
    atomicAdd(o + 3, val * __uint_as_float(s.y & 0xFFFF0000u));
}

__global__ __launch_bounds__(256) void relu_kernel(float* __restrict__ out, int n4) {
    const int i = blockIdx.x * blockDim.x + threadIdx.x;
    if (i < n4) {
        float4 v = ((float4*)out)[i];
        v.x = fmaxf(v.x, 0.f); v.y = fmaxf(v.y, 0.f);
        v.z = fmaxf(v.z, 0.f); v.w = fmaxf(v.w, 0.f);
        ((float4*)out)[i] = v;
    }
}

extern "C" void kernel_launch(void* const* d_in, const int* in_sizes, int n_in,
                              void* d_out, int out_size, void* d_ws, size_t ws_size,
                              hipStream_t stream) {
    const float* x        = (const float*)d_in[0];
    const float* w        = (const float*)d_in[1];
    const float* edge_val = (const float*)d_in[2];
    const int*   edge_src = (const int*)d_in[3];
    const int*   edge_dst = (const int*)d_in[4];
    float* out = (float*)d_out;

    const int n_nodes = in_sizes[0] / F_IN;   // 100000
    const int n_edges = in_sizes[2];          // 1600000
    const int nb = (n_nodes + NPB - 1) >> NPB_SHIFT;   // 782 buckets
    const int T  = (n_edges + TILE - 1) / TILE;        // 196 tiles
    const int G  = (n_nodes + ROWS_PER_BLOCK - 1) / ROWS_PER_BLOCK;  // 1563

    // Workspace: support bf16 (12.8 MB) | sorted (12.85 MB) | toff (0.61 MB)
    char* p = (char*)d_ws;
    unsigned short* support = (unsigned short*)p;
    p += (size_t)n_nodes * F_OUT * sizeof(unsigned short);
    p = (char*)(((size_t)p + 15) & ~(size_t)15);
    int2* sorted = (int2*)p;  p += (size_t)T * TILE * sizeof(int2);
    int*  toff   = (int*)p;   p += (size_t)T * (nb + 1) * sizeof(int);
    const size_t ws_needed = (size_t)(p - (char*)d_ws);

    const bool ok = (ws_size >= ws_needed) && (nb <= BCAP) && (n_nodes < (1 << 20))
                    && (T <= TMAX);
    if (ok) {
        fused_kernel<<<T + G, BSTH, 0, stream>>>(x, w, support, n_nodes,
                                                 edge_val, edge_src, edge_dst,
                                                 toff, sorted, n_edges, nb, T);
        baccum_kernel<<<nb, 512, 0, stream>>>(support, sorted, toff, out,
                                              n_nodes, T, nb);
    } else {
        // gemm only (T=0 -> all blocks take the gemm role)
        fused_kernel<<<G, BSTH, 0, stream>>>(x, w, support, n_nodes,
                                             edge_val, edge_src, edge_dst,
                                             nullptr, nullptr, n_edges, nb, 0);
        hipMemsetAsync(d_out, 0, (size_t)out_size * sizeof(float), stream);
        const long st = (long)n_edges * 16;
        scatter_kernel<<<(int)((st + 255) / 256), 256, 0, stream>>>(
            support, edge_val, edge_src, edge_dst, out, n_edges);
        const int n4o = out_size / 4;
        relu_kernel<<<(n4o + 255) / 256, 256, 0, stream>>>(out, n4o);
    }
}

// Round 12
// 175.629 us; speedup vs baseline: 1.3830x; 1.0228x over previous
//
#include <hip/hip_runtime.h>

#define F_IN 128
#define F_OUT 64
#define GROWS 128        // rows per gemm block (2 rows/thread at 1024 thr)
#define XSTRIDE 33       // float4 per x_lds row (132 floats, 16B aligned, padded)

#define NPB 128          // nodes per bucket
#define NPB_SHIFT 7
#define BCAP 800         // max buckets (nb = 782)
#define ECAP 2560        // edges staged per LDS chunk in baccum
#define TILE 8192        // edges per tile in multisplit
#define BSTH 1024        // fused-kernel threads
#define TMAX 256         // max tiles (T = ceil(E/TILE) = 196)

// fp32 -> bf16 round-to-nearest-even.
__device__ inline unsigned short f2bf(float f) {
    const unsigned u = __float_as_uint(f);
    return (unsigned short)((u + 0x7FFFu + ((u >> 16) & 1u)) >> 16);
}

// Shared-memory union: gemm role vs multisplit role (whole-block roles).
struct GemmSh {
    float4 w[F_IN * F_OUT / 4];              // 32 KB
    float4 xt[GROWS * XSTRIDE];              // 67.6 KB
};
struct ScatSh {
    int2 ebuf2[TILE];                        // 64 KB (rank-permuted records)
    int  h[BCAP];                            // 3.2 KB
    int  lcur[BCAP];                         // 3.2 KB
    int  wsum[16];
    int  woff[16];
};
union FusedSh { GemmSh g; ScatSh s; };       // ~100 KB -> 1 block/CU (160 KB LDS)

// ---------------------------------------------------------------------------
// Fused kernel: blocks [0,T) = tile-private edge multisplit; blocks [T,T+G) =
// support(bf16) = x @ weight (128-row tile, 2 rows/thread: the wv b128 LDS
// read is amortized over 8 FMAs). Scatter blocks (196 < 256 CUs) are
// unaffected by the 1-block/CU occupancy.
// ---------------------------------------------------------------------------
__global__ __launch_bounds__(BSTH) void fused_kernel(const float* __restrict__ x,
                                                     const float* __restrict__ w,
                                                     unsigned short* __restrict__ support,
                                                     int n_nodes,
                                                     const float* __restrict__ edge_val,
                                                     const int* __restrict__ edge_src,
                                                     const int* __restrict__ edge_dst,
                                                     int* __restrict__ toff,
                                                     int2* __restrict__ sorted,
                                                     int n_edges, int nb, int T) {
    __shared__ FusedSh u;
    const int tid = threadIdx.x;

    if ((int)blockIdx.x >= T) {
        // ================= gemm role =================
        const int row0 = (blockIdx.x - T) * GROWS;

        {   // stage weight: 2048 f4, 2 per thread
            const float4* w4 = (const float4*)w;
            #pragma unroll
            for (int i = tid; i < F_IN * F_OUT / 4; i += BSTH) u.g.w[i] = w4[i];
        }
        {   // stage x tile: 128 rows x 32 f4, 4 per thread
            const float4* x4 = (const float4*)x;
            #pragma unroll
            for (int i = tid; i < GROWS * (F_IN / 4); i += BSTH) {
                const int r  = i >> 5;
                const int k4 = i & 31;
                const int row = row0 + r;
                float4 v = make_float4(0.f, 0.f, 0.f, 0.f);
                if (row < n_nodes) v = x4[(size_t)row * (F_IN / 4) + k4];
                u.g.xt[r * XSTRIDE + k4] = v;
            }
        }
        __syncthreads();

        const int tf = tid & 15;     // feats 4tf..4tf+3
        const int tr = tid >> 4;     // rows tr and tr+64
        const float* xs = (const float*)u.g.xt;

        float acc[2][4] = {};
        #pragma unroll 4
        for (int k = 0; k < F_IN; ++k) {
            const float4 wv = u.g.w[k * 16 + tf];
            const float x0 = xs[tr * (XSTRIDE * 4) + k];
            const float x1 = xs[(tr + 64) * (XSTRIDE * 4) + k];
            acc[0][0] += x0 * wv.x; acc[0][1] += x0 * wv.y; acc[0][2] += x0 * wv.z; acc[0][3] += x0 * wv.w;
            acc[1][0] += x1 * wv.x; acc[1][1] += x1 * wv.y; acc[1][2] += x1 * wv.z; acc[1][3] += x1 * wv.w;
        }
        #pragma unroll
        for (int i = 0; i < 2; ++i) {
            const int row = row0 + tr + 64 * i;
            if (row < n_nodes) {
                ushort4 o;
                o.x = f2bf(acc[i][0]); o.y = f2bf(acc[i][1]);
                o.z = f2bf(acc[i][2]); o.w = f2bf(acc[i][3]);
                *(ushort4*)&support[(size_t)row * F_OUT + 4 * tf] = o;
            }
        }
        return;
    }

    // ================= multisplit role =================
    const int te  = blockIdx.x * TILE;
    const int cnt = min(TILE, n_edges - te);

    for (int i = tid; i < BCAP; i += BSTH) u.s.h[i] = 0;
    __syncthreads();

    // Pass A: load edges into REGISTERS (2 int4-tiles/thread) + LDS hist.
    const int cnt4 = cnt >> 2;
    const int4*   s4 = (const int4*)(edge_src + te);
    const int4*   d4 = (const int4*)(edge_dst + te);
    const float4* v4 = (const float4*)(edge_val + te);
    int4 rs[2], rd[2]; float4 rv[2];
    #pragma unroll
    for (int it = 0; it < 2; ++it) {
        const int t = tid + it * BSTH;
        if (t < cnt4) {
            rs[it] = s4[t]; rd[it] = d4[t]; rv[it] = v4[t];
            atomicAdd(&u.s.h[rd[it].x >> NPB_SHIFT], 1);
            atomicAdd(&u.s.h[rd[it].y >> NPB_SHIFT], 1);
            atomicAdd(&u.s.h[rd[it].z >> NPB_SHIFT], 1);
            atomicAdd(&u.s.h[rd[it].w >> NPB_SHIFT], 1);
        }
    }
    if (tid == 0) {   // tail (<=3 edges): hist only, ranked in pass B
        for (int e = cnt4 << 2; e < cnt; ++e)
            atomicAdd(&u.s.h[edge_dst[te + e] >> NPB_SHIFT], 1);
    }
    __syncthreads();

    // Shuffle-based block scan of bucket counts (16 waves).
    const int v = (tid < nb) ? u.s.h[tid] : 0;
    int s = v;
    #pragma unroll
    for (int off = 1; off < 64; off <<= 1) {
        const int t = __shfl_up(s, off, 64);
        if ((tid & 63) >= off) s += t;
    }
    const int wave = tid >> 6;
    if ((tid & 63) == 63) u.s.wsum[wave] = s;
    __syncthreads();
    if (tid < 16) {
        const int ws = u.s.wsum[tid];
        int sc = ws;
        #pragma unroll
        for (int off = 1; off < 16; off <<= 1) {
            const int t = __shfl_up(sc, off, 64);
            if (tid >= off) sc += t;
        }
        u.s.woff[tid] = sc - ws;   // exclusive wave offset
    }
    __syncthreads();

    int* trow = toff + (size_t)blockIdx.x * (nb + 1);
    if (tid < nb) {
        const int start = s + u.s.woff[wave] - v;   // exclusive start
        u.s.lcur[tid] = start;
        trow[tid] = start;
    }
    if (tid == 0) trow[nb] = cnt;
    __syncthreads();

    // Pass B: rank (LDS cursor) and write records DIRECTLY permuted into LDS.
    #pragma unroll
    for (int it = 0; it < 2; ++it) {
        const int t = tid + it * BSTH;
        if (t < cnt4) {
            int b, r;
            b = rd[it].x >> NPB_SHIFT; r = atomicAdd(&u.s.lcur[b], 1);
            u.s.ebuf2[r] = make_int2(rs[it].x | ((rd[it].x & (NPB - 1)) << 20), __float_as_int(rv[it].x));
            b = rd[it].y >> NPB_SHIFT; r = atomicAdd(&u.s.lcur[b], 1);
            u.s.ebuf2[r] = make_int2(rs[it].y | ((rd[it].y & (NPB - 1)) << 20), __float_as_int(rv[it].y));
            b = rd[it].z >> NPB_SHIFT; r = atomicAdd(&u.s.lcur[b], 1);
            u.s.ebuf2[r] = make_int2(rs[it].z | ((rd[it].z & (NPB - 1)) << 20), __float_as_int(rv[it].z));
            b = rd[it].w >> NPB_SHIFT; r = atomicAdd(&u.s.lcur[b], 1);
            u.s.ebuf2[r] = make_int2(rs[it].w | ((rd[it].w & (NPB - 1)) << 20), __float_as_int(rv[it].w));
        }
    }
    if (tid == 0) {   // tail
        for (int e = cnt4 << 2; e < cnt; ++e) {
            const int dd = edge_dst[te + e];
            const int b = dd >> NPB_SHIFT;
            const int r = atomicAdd(&u.s.lcur[b], 1);
            u.s.ebuf2[r] = make_int2(edge_src[te + e] | ((dd & (NPB - 1)) << 20),
                                     __float_as_int(edge_val[te + e]));
        }
    }
    __syncthreads();

    // Pass C: stream the sorted tile to its private region (coalesced).
    for (int k = tid; k < cnt; k += BSTH)
        sorted[(size_t)te + k] = u.s.ebuf2[k];
}

// ---------------------------------------------------------------------------
// baccum v5: 8 lanes per edge, uint4 (16 B = 8 bf16 feats) per lane ->
// one wave serves 8 edges per vmem/LDS instruction (was 4). Register acc
// (2 nodes x 8 feats / lane), fused ReLU.
// ---------------------------------------------------------------------------
__global__ __launch_bounds__(512) void baccum_kernel(const unsigned short* __restrict__ support,
                                                     const int2* __restrict__ sorted,
                                                     const int* __restrict__ toff,
                                                     float* __restrict__ out,
                                                     int n_nodes, int T, int nb) {
    __shared__ int2 ebuf[ECAP];
    __shared__ int2 ebuf2[ECAP];
    __shared__ int tstart[TMAX];
    __shared__ int toffb[TMAX];
    __shared__ int wsum3[4];
    __shared__ int total_s;
    __shared__ int hist[NPB];
    __shared__ int node_off[NPB + 1];
    __shared__ int cursor[NPB];
    __shared__ int wsum2[2];

    const int tid = threadIdx.x;
    const int b = blockIdx.x;

    int mycnt = 0, myoff = 0;
    if (tid < TMAX) {
        if (tid < T) {
            const int s0 = toff[(size_t)tid * (nb + 1) + b];
            const int e0 = toff[(size_t)tid * (nb + 1) + b + 1];
            toffb[tid] = s0;
            mycnt = e0 - s0;
        }
        int s = mycnt;
        #pragma unroll
        for (int off = 1; off < 64; off <<= 1) {
            const int t = __shfl_up(s, off, 64);
            if ((tid & 63) >= off) s += t;
        }
        if ((tid & 63) == 63) wsum3[tid >> 6] = s;
        myoff = s - mycnt;
    }
    __syncthreads();
    if (tid < TMAX && tid < T) {
        int add = 0;
        const int wv = tid >> 6;
        for (int q = 0; q < wv; ++q) add += wsum3[q];
        tstart[tid] = myoff + add;
    }
    if (tid == 0) total_s = wsum3[0] + wsum3[1] + wsum3[2] + wsum3[3];
    __syncthreads();
    const int total = total_s;

    const int g8 = tid >> 3;        // group 0..63 (owns nodes g8, g8+64)
    const int q  = tid & 7;         // uint4 slot: feats 8q..8q+7
    const uint4* sup = (const uint4*)support;   // row = 8 uint4 = 128 B

    float4 accA[2], accB[2];        // node j: feats 8q..8q+3 / 8q+4..8q+7
    #pragma unroll
    for (int j = 0; j < 2; ++j) {
        accA[j] = make_float4(0.f, 0.f, 0.f, 0.f);
        accB[j] = make_float4(0.f, 0.f, 0.f, 0.f);
    }

    for (int cb = 0; cb < total; cb += ECAP) {
        const int cnt = min(ECAP, total - cb);

        __syncthreads();
        if (tid < NPB) hist[tid] = 0;
        __syncthreads();

        // Stage + histogram (tile via binary search over tstart).
        for (int i = tid; i < cnt; i += 512) {
            const int g = cb + i;
            int lo = 0, hi = T - 1;
            while (lo < hi) {
                const int mid = (lo + hi + 1) >> 1;
                if (tstart[mid] <= g) lo = mid; else hi = mid - 1;
            }
            const int2 ev = sorted[(size_t)lo * TILE + toffb[lo] + (g - tstart[lo])];
            ebuf[i] = ev;
            atomicAdd(&hist[((unsigned)ev.x) >> 20], 1);
        }
        __syncthreads();

        // Shuffle scan of 128 node bins (2 waves).
        {
            int v = 0;
            if (tid < NPB) v = hist[tid];
            int s = v;
            if (tid < NPB) {
                #pragma unroll
                for (int off = 1; off < 64; off <<= 1) {
                    const int t = __shfl_up(s, off, 64);
                    if ((tid & 63) >= off) s += t;
                }
                if ((tid & 63) == 63) wsum2[tid >> 6] = s;
            }
            __syncthreads();
            if (tid < NPB) {
                const int incl = s + ((tid >= 64) ? wsum2[0] : 0);
                node_off[tid + 1] = incl;
                cursor[tid] = incl - v;
                if (tid == 0) node_off[0] = 0;
            }
        }
        __syncthreads();

        // Permute into dstLocal-grouped ebuf2 (LDS only).
        for (int i = tid; i < cnt; i += 512) {
            const int2 ev = ebuf[i];
            const int r = atomicAdd(&cursor[((unsigned)ev.x) >> 20], 1);
            ebuf2[r] = ev;
        }
        __syncthreads();

        // Register gather, 8-wide independent uint4 batches.
        #pragma unroll
        for (int j = 0; j < 2; ++j) {
            const int nl = g8 + 64 * j;
            int k = node_off[nl];
            const int ke = node_off[nl + 1];
            float4 aA = accA[j], aB = accB[j];
            while (k + 8 <= ke) {
                int2 e[8];
                uint4 s[8];
                #pragma unroll
                for (int u2 = 0; u2 < 8; ++u2) e[u2] = ebuf2[k + u2];      // broadcast
                #pragma unroll
                for (int u2 = 0; u2 < 8; ++u2)
                    s[u2] = sup[(size_t)(e[u2].x & 0xFFFFF) * 8 + q];      // independent
                #pragma unroll
                for (int u2 = 0; u2 < 8; ++u2) {
                    const float v = __int_as_float(e[u2].y);
                    aA.x += v * __uint_as_float(s[u2].x << 16);
                    aA.y += v * __uint_as_float(s[u2].x & 0xFFFF0000u);
                    aA.z += v * __uint_as_float(s[u2].y << 16);
                    aA.w += v * __uint_as_float(s[u2].y & 0xFFFF0000u);
                    aB.x += v * __uint_as_float(s[u2].z << 16);
                    aB.y += v * __uint_as_float(s[u2].z & 0xFFFF0000u);
                    aB.z += v * __uint_as_float(s[u2].w << 16);
                    aB.w += v * __uint_as_float(s[u2].w & 0xFFFF0000u);
                }
                k += 8;
            }
            for (; k < ke; ++k) {
                const int2 e0 = ebuf2[k];
                const uint4 s0 = sup[(size_t)(e0.x & 0xFFFFF) * 8 + q];
                const float v0 = __int_as_float(e0.y);
                aA.x += v0 * __uint_as_float(s0.x << 16);
                aA.y += v0 * __uint_as_float(s0.x & 0xFFFF0000u);
                aA.z += v0 * __uint_as_float(s0.y << 16);
                aA.w += v0 * __uint_as_float(s0.y & 0xFFFF0000u);
                aB.x += v0 * __uint_as_float(s0.z << 16);
                aB.y += v0 * __uint_as_float(s0.z & 0xFFFF0000u);
                aB.z += v0 * __uint_as_float(s0.w << 16);
                aB.w += v0 * __uint_as_float(s0.w & 0xFFFF0000u);
            }
            accA[j] = aA; accB[j] = aB;
        }
    }

    // Writeout (empty buckets write zeros; ReLU(0)=0 matches segment_sum).
    const int base = b << NPB_SHIFT;
    #pragma unroll
    for (int j = 0; j < 2; ++j) {
        const int node = base + g8 + 64 * j;
        if (node < n_nodes) {
            float4 vA = accA[j], vB = accB[j];
            vA.x = fmaxf(vA.x, 0.f); vA.y = fmaxf(vA.y, 0.f);
            vA.z = fmaxf(vA.z, 0.f); vA.w = fmaxf(vA.w, 0.f);
            vB.x = fmaxf(vB.x, 0.f); vB.y = fmaxf(vB.y, 0.f);
            vB.z = fmaxf(vB.z, 0.f); vB.w = fmaxf(vB.w, 0.f);
            ((float4*)out)[(size_t)node * 16 + 2 * q + 0] = vA;
            ((float4*)out)[(size_t)node * 16 + 2 * q + 1] = vB;
        }
    }
}

// ---------------------------------------------------------------------------
// Fallback: atomic path with bf16 support.
// ---------------------------------------------------------------------------
__global__ __launch_bounds__(256) void scatter_kernel(const unsigned short* __restrict__ support,
                                                      const float* __restrict__ edge_val,
                                                      const int* __restrict__ edge_src,
                                                      const int* __restrict__ edge_dst,
                                                      float* __restrict__ out,
                                                      int n_edges) {
    const long gid = (long)blockIdx.x * blockDim.x + threadIdx.x;
    const int e = (int)(gid >> 4);
    if (e >= n_edges) return;
    const int q = (int)(gid & 15);
    const int src   = edge_src[e];
    const int dst   = edge_dst[e];
    const float val = edge_val[e];
    const uint2 s = ((const uint2*)support)[(size_t)src * 16 + q];
    float* o = &out[(size_t)dst * F_OUT + q * 4];
    atomicAdd(o + 0, val * __uint_as_float(s.x << 16));
    atomicAdd(o + 1, val * __uint_as_float(s.x & 0xFFFF0000u));
    atomicAdd(o + 2, val * __uint_as_float(s.y << 16));
    atomicAdd(o + 3, val * __uint_as_float(s.y & 0xFFFF0000u));
}

__global__ __launch_bounds__(256) void relu_kernel(float* __restrict__ out, int n4) {
    const int i = blockIdx.x * blockDim.x + threadIdx.x;
    if (i < n4) {
        float4 v = ((float4*)out)[i];
        v.x = fmaxf(v.x, 0.f); v.y = fmaxf(v.y, 0.f);
        v.z = fmaxf(v.z, 0.f); v.w = fmaxf(v.w, 0.f);
        ((float4*)out)[i] = v;
    }
}

extern "C" void kernel_launch(void* const* d_in, const int* in_sizes, int n_in,
                              void* d_out, int out_size, void* d_ws, size_t ws_size,
                              hipStream_t stream) {
    const float* x        = (const float*)d_in[0];
    const float* w        = (const float*)d_in[1];
    const float* edge_val = (const float*)d_in[2];
    const int*   edge_src = (const int*)d_in[3];
    const int*   edge_dst = (const int*)d_in[4];
    float* out = (float*)d_out;

    const int n_nodes = in_sizes[0] / F_IN;   // 100000
    const int n_edges = in_sizes[2];          // 1600000
    const int nb = (n_nodes + NPB - 1) >> NPB_SHIFT;   // 782 buckets
    const int T  = (n_edges + TILE - 1) / TILE;        // 196 tiles
    const int G  = (n_nodes + GROWS - 1) / GROWS;      // 782 gemm blocks

    // Workspace: support bf16 (12.8 MB) | sorted (12.85 MB) | toff (0.61 MB)
    char* p = (char*)d_ws;
    unsigned short* support = (unsigned short*)p;
    p += (size_t)n_nodes * F_OUT * sizeof(unsigned short);
    p = (char*)(((size_t)p + 15) & ~(size_t)15);
    int2* sorted = (int2*)p;  p += (size_t)T * TILE * sizeof(int2);
    int*  toff   = (int*)p;   p += (size_t)T * (nb + 1) * sizeof(int);
    const size_t ws_needed = (size_t)(p - (char*)d_ws);

    const bool ok = (ws_size >= ws_needed) && (nb <= BCAP) && (n_nodes < (1 << 20))
                    && (T <= TMAX);
    if (ok) {
        fused_kernel<<<T + G, BSTH, 0, stream>>>(x, w, support, n_nodes,
                                                 edge_val, edge_src, edge_dst,
                                                 toff, sorted, n_edges, nb, T);
        baccum_kernel<<<nb, 512, 0, stream>>>(support, sorted, toff, out,
                                              n_nodes, T, nb);
    } else {
        // gemm only (T=0 -> all blocks take the gemm role)
        fused_kernel<<<G, BSTH, 0, stream>>>(x, w, support, n_nodes,
                                             edge_val, edge_src, edge_dst,
                                             nullptr, nullptr, n_edges, nb, 0);
        hipMemsetAsync(d_out, 0, (size_t)out_size * sizeof(float), stream);
        const long st = (long)n_edges * 16;
        scatter_kernel<<<(int)((st + 255) / 256), 256, 0, stream>>>(
            support, edge_val, edge_src, edge_dst, out, n_edges);
        const int n4o = out_size / 4;
        relu_kernel<<<(n4o + 255) / 256, 256, 0, stream>>>(out, n4o);
    }
}